// Round 23
// baseline (902.444 us; speedup 1.0000x reference)
//
#include <hip/hip_runtime.h>
#include <stdint.h>

#define CONF_T 0.05f
#define KSEL 1000
#define CAND_CAP 2048
#define ROWS 128
#define TPB 1024
#define SH_A 21
#define SH_B 10

// ---- wave-parallel crossing over 2048 LDS bins (verified R19-R22) ----
__device__ __forceinline__ void crossing2048(
    const uint32_t* __restrict__ hh, uint32_t rem, volatile uint32_t* __restrict__ res)
{
    __syncthreads();
    if (threadIdx.x < 64) {
        const int lane = threadIdx.x;
        uint32_t s = 0;
        #pragma unroll 8
        for (int j = 0; j < 32; ++j) s += hh[lane * 32 + j];
        uint32_t suf = s;
        #pragma unroll
        for (int off = 1; off < 64; off <<= 1) {
            uint32_t t = __shfl_down(suf, off);
            if (lane + off < 64) suf += t;
        }
        unsigned long long m = __ballot(suf >= rem);
        int L = (m == 0) ? 0 : (63 - __clzll(m));
        uint32_t cum_above = (L < 63) ? __shfl(suf, L + 1) : 0u;

        uint32_t binv = (lane < 32) ? hh[L * 32 + lane] : 0u;
        uint32_t suf2 = binv;
        #pragma unroll
        for (int off = 1; off < 32; off <<= 1) {
            uint32_t t = __shfl_down(suf2, off);
            if (lane + off < 32) suf2 += t;
        }
        unsigned long long m2 = __ballot(lane < 32 && (cum_above + suf2) >= rem);
        int j = (m2 == 0) ? 0 : (63 - __clzll(m2));
        uint32_t above2 = cum_above + ((j < 31) ? __shfl(suf2, j + 1) : 0u);
        if (lane == 0) {
            res[0] = (uint32_t)(L * 32 + j);
            res[1] = rem - above2;
        }
    }
    __syncthreads();
}

// One dispatch: blocks [0,B) = per-batch selectors (spin on tile flags);
// blocks [B, B+B*tilesPB) = argmax tile workers. Worker wk: batch = wk%B (XCD-aligned
// with selector when B==8), tile = wk/B. Flags: set-by-worker(1), cleared-by-selector(0)
// -> replay-safe with no init kernel (0xAA poison != 1 just makes first call wait correctly).
__global__ __launch_bounds__(TPB) void fused_kernel(
    const float* __restrict__ probs, const float* __restrict__ anchors,
    const float* __restrict__ offsets, const float* __restrict__ window,
    float* __restrict__ sc, int* __restrict__ cls, uint32_t* __restrict__ flags,
    float* __restrict__ out, int N, int B, int tilesPB)
{
    __shared__ float    tile[ROWS * 81];
    __shared__ uint32_t hh[2048];
    __shared__ uint32_t res[2];
    __shared__ uint32_t sh_vA, sh_remA, sh_cnt;
    __shared__ uint64_t cand[CAND_CAP];

    const int tid  = threadIdx.x;
    const int lane = tid & 63;

    if ((int)blockIdx.x >= B) {
        // ================= WORKER: one 128-row argmax tile =================
        const int wk = blockIdx.x - B;
        const int bb = wk % B;
        const int t  = wk / B;
        const int r0l = t * ROWS;
        const int rows_here = min(ROWS, N - r0l);
        const size_t r0 = (size_t)bb * N + r0l;

        if (rows_here > 0) {
            const float4* src = reinterpret_cast<const float4*>(probs + r0 * 80);
            const int nf4 = rows_here * 20;
            for (int f = tid; f < nf4; f += TPB) {
                float4 v = src[f];
                int fo = f * 4, row = fo / 80, col = fo - row * 80;
                float* dst = &tile[row * 81 + col];
                dst[0] = v.x; dst[1] = v.y; dst[2] = v.z; dst[3] = v.w;
            }
            __syncthreads();
            const int row = tid >> 3, g = tid & 7;   // 8 lanes per row
            if (row < rows_here) {
                const float* rp = &tile[row * 81 + g * 10];
                float bv = rp[0]; int bc = g * 10;
                #pragma unroll
                for (int j = 1; j < 10; ++j) {
                    float v = rp[j];
                    if (v > bv) { bv = v; bc = g * 10 + j; }   // first-max within segment
                }
                #pragma unroll
                for (int off = 4; off >= 1; off >>= 1) {       // first-max across segments
                    float ov = __shfl_down(bv, off);
                    int   oc = __shfl_down(bc, off);
                    if ((g + off) < 8 && (ov > bv || (ov == bv && oc < bc))) { bv = ov; bc = oc; }
                }
                if (g == 0) { sc[r0 + row] = bv; cls[r0 + row] = bc; }
            }
            __syncthreads();
        }
        __threadfence();                                       // release sc/cls
        if (tid == 0) atomicExch(&flags[(size_t)bb * tilesPB + t], 1u);
        return;
    }

    // ================= SELECTOR: per-batch top-K =================
    const int bb = blockIdx.x;
    uint32_t* fl = flags + (size_t)bb * tilesPB;

    for (;;) {
        int mine = 1;
        for (int j = tid; j < tilesPB; j += TPB)
            if (atomicAdd(&fl[j], 0u) != 1u) mine = 0;
        if (__syncthreads_and(mine)) break;
    }
    __threadfence();                                           // acquire sc/cls
    for (int j = tid; j < tilesPB; j += TPB) atomicExch(&fl[j], 0u);   // clear for next call

    const float* sbase = sc + (size_t)bb * N;
    const float4* s4 = reinterpret_cast<const float4*>(sbase);
    const int n4 = N >> 2;

    // ---- pass-A histogram (bits[31:21]) with one-round wave aggregation (verified R22)
    for (int i = tid; i < 2048; i += TPB) hh[i] = 0u;
    if (tid == 0) sh_cnt = 0u;
    __syncthreads();
    for (int base = 0; base < n4; base += TPB) {
        const int f = base + tid;
        const bool act = (f < n4);
        float4 v = act ? s4[f] : make_float4(0.f, 0.f, 0.f, 0.f);
        #pragma unroll
        for (int j = 0; j < 4; ++j) {
            uint32_t bits = __float_as_uint(j==0 ? v.x : j==1 ? v.y : j==2 ? v.z : v.w);
            uint32_t bin  = bits >> SH_A;
            unsigned long long actm = __ballot(act);
            if (actm) {
                int ldr = __ffsll(actm) - 1;
                uint32_t b0 = __shfl(bin, ldr);
                unsigned long long eq = __ballot(act && bin == b0);
                if (lane == ldr) atomicAdd(&hh[b0], (uint32_t)__popcll(eq));
                if (act && bin != b0) atomicAdd(&hh[bin], 1u);
            }
        }
    }
    for (int i = (n4 << 2) + tid; i < N; i += TPB)             // scalar tail (N%4)
        atomicAdd(&hh[__float_as_uint(sbase[i]) >> SH_A], 1u);
    crossing2048(hh, KSEL, res);
    if (tid == 0) { sh_vA = res[0]; sh_remA = res[1]; }
    __syncthreads();
    const uint32_t vA = sh_vA, remA = sh_remA;

    // ---- pass-B histogram (bits[20:10]) over prefix-A matches
    for (int i = tid; i < 2048; i += TPB) hh[i] = 0u;
    __syncthreads();
    for (int f = tid; f < n4; f += TPB) {
        float4 v = s4[f];
        #pragma unroll
        for (int j = 0; j < 4; ++j) {
            uint32_t bits = __float_as_uint(j==0 ? v.x : j==1 ? v.y : j==2 ? v.z : v.w);
            if ((bits >> SH_A) == vA)
                atomicAdd(&hh[(bits >> SH_B) & 0x7FFu], 1u);
        }
    }
    for (int i = (n4 << 2) + tid; i < N; i += TPB) {
        uint32_t bits = __float_as_uint(sbase[i]);
        if ((bits >> SH_A) == vA) atomicAdd(&hh[(bits >> SH_B) & 0x7FFu], 1u);
    }
    crossing2048(hh, remA, res);
    const uint32_t t_lo = (vA << SH_A) | (res[0] << SH_B);

    // ---- gather candidates (wave-aggregated positions, verified R21)
    for (int i = tid; i < CAND_CAP; i += TPB) cand[i] = ~0ull;
    __syncthreads();
    for (int base = 0; base < n4; base += TPB) {
        const int f = base + tid;
        const bool act = (f < n4);
        float4 v = act ? s4[f] : make_float4(0.f, 0.f, 0.f, 0.f);
        #pragma unroll
        for (int j = 0; j < 4; ++j) {
            uint32_t bits = __float_as_uint(j==0 ? v.x : j==1 ? v.y : j==2 ? v.z : v.w);
            bool hit = act && (bits >= t_lo);
            unsigned long long m = __ballot(hit);
            if (m) {
                int ldr = __ffsll(m) - 1;
                uint32_t pbase = 0;
                if (lane == ldr) pbase = atomicAdd(&sh_cnt, (uint32_t)__popcll(m));
                pbase = __shfl(pbase, ldr);
                if (hit) {
                    uint32_t pos = pbase + (uint32_t)__popcll(m & ((1ull << lane) - 1ull));
                    if (pos < CAND_CAP)
                        cand[pos] = ((uint64_t)(~bits) << 32) | (uint64_t)(uint32_t)(4*f + j);
                }
            }
        }
    }
    for (int i = (n4 << 2) + tid; i < N; i += TPB) {
        uint32_t bits = __float_as_uint(sbase[i]);
        if (bits >= t_lo) {
            uint32_t pos = atomicAdd(&sh_cnt, 1u);
            if (pos < CAND_CAP)
                cand[pos] = ((uint64_t)(~bits) << 32) | (uint64_t)(uint32_t)i;
        }
    }
    __syncthreads();
    uint32_t G = sh_cnt;
    if (G > CAND_CAP) G = CAND_CAP;

    // ---- bitonic sort ascending: (~bits, idx) => score desc, idx asc (verified R21)
    for (unsigned k = 2; k <= CAND_CAP; k <<= 1) {
        for (unsigned j = k >> 1; j > 0; j >>= 1) {
            for (unsigned i = tid; i < CAND_CAP; i += TPB) {
                unsigned ixj = i ^ j;
                if (ixj > i) {
                    uint64_t a = cand[i], c2 = cand[ixj];
                    bool up = ((i & k) == 0);
                    if ((a > c2) == up) { cand[i] = c2; cand[ixj] = a; }
                }
            }
            __syncthreads();
        }
    }

    // ---- decode + write: sorted position IS the rank (verified)
    const float wy1 = window[0], wx1 = window[1], wy2 = window[2], wx2 = window[3];
    const int BK = B * KSEL;
    float* o_ai = out;             // [B,K,2] (b, idx)
    float* o_bx = out + 2 * BK;    // [B,K,4]
    float* o_cl = out + 6 * BK;
    float* o_sc = out + 7 * BK;
    float* o_vd = out + 8 * BK;

    const uint32_t W = (G < KSEL) ? G : KSEL;
    for (uint32_t r = tid; r < W; r += TPB) {
        const uint64_t kc = cand[r];
        if (kc == ~0ull) continue;

        uint32_t idx   = (uint32_t)kc;
        uint32_t sbits = ~(uint32_t)(kc >> 32);
        float score    = __uint_as_float(sbits);

        size_t base = (size_t)bb * N + idx;
        const float4 a = *reinterpret_cast<const float4*>(anchors + base * 4);
        const float4 o = *reinterpret_cast<const float4*>(offsets + base * 4);

        float h  = a.z - a.x;
        float w  = a.w - a.y;
        float cy = a.x + 0.5f * h + o.x * h;
        float cx = a.y + 0.5f * w + o.y * w;
        float hh2 = h * expf(o.z);
        float ww  = w * expf(o.w);
        float y1 = fminf(fmaxf(cy - 0.5f * hh2, wy1), wy2);
        float x1 = fminf(fmaxf(cx - 0.5f * ww,  wx1), wx2);
        float y2 = fminf(fmaxf(cy + 0.5f * hh2, wy1), wy2);
        float x2 = fminf(fmaxf(cx + 0.5f * ww,  wx1), wx2);

        int ok = bb * KSEL + (int)r;
        o_ai[ok*2 + 0] = (float)bb;
        o_ai[ok*2 + 1] = (float)idx;
        o_bx[ok*4 + 0] = y1;
        o_bx[ok*4 + 1] = x1;
        o_bx[ok*4 + 2] = y2;
        o_bx[ok*4 + 3] = x2;
        o_cl[ok] = (float)cls[base];
        o_sc[ok] = score;
        o_vd[ok] = (score > CONF_T) ? 1.0f : 0.0f;
    }
}

extern "C" void kernel_launch(void* const* d_in, const int* in_sizes, int n_in,
                              void* d_out, int out_size, void* d_ws, size_t ws_size,
                              hipStream_t stream)
{
    const float* anchors = (const float*)d_in[0];
    const float* probs   = (const float*)d_in[1];
    const float* offsets = (const float*)d_in[2];
    const float* window  = (const float*)d_in[3];

    const int B = out_size / (9 * KSEL);
    const int N = in_sizes[0] / (B * 4);
    const int total = B * N;
    const int tilesPB = (N + ROWS - 1) / ROWS;

    float*    sc    = (float*)d_ws;
    int*      cls   = (int*)((char*)d_ws + (size_t)total * 4);
    uint32_t* flags = (uint32_t*)((char*)d_ws + (size_t)total * 8);

    const int grid = B + B * tilesPB;
    hipLaunchKernelGGL(fused_kernel, dim3(grid), dim3(TPB), 0, stream,
                       probs, anchors, offsets, window,
                       sc, cls, flags, (float*)d_out, N, B, tilesPB);
}

// Round 24
// 517.095 us; speedup vs baseline: 1.7452x; 1.7452x over previous
//
#include <hip/hip_runtime.h>
#include <stdint.h>

#define CONF_T 0.05f
#define KSEL 1000
#define CAND_CAP 2048
#define ROWS 128
#define TPW 512
#define SH_A 21
#define SH_B 10

__global__ __launch_bounds__(64) void zero_done_kernel(uint32_t* __restrict__ done, int B)
{
    if ((int)threadIdx.x < B) done[threadIdx.x] = 0u;
}

// ---- wave-parallel crossing over 2048 LDS bins (verified R19-R22) ----
__device__ __forceinline__ void crossing2048(
    const uint32_t* __restrict__ hh, uint32_t rem, volatile uint32_t* __restrict__ res)
{
    __syncthreads();
    if (threadIdx.x < 64) {
        const int lane = threadIdx.x;
        uint32_t s = 0;
        #pragma unroll 8
        for (int j = 0; j < 32; ++j) s += hh[lane * 32 + j];
        uint32_t suf = s;
        #pragma unroll
        for (int off = 1; off < 64; off <<= 1) {
            uint32_t t = __shfl_down(suf, off);
            if (lane + off < 64) suf += t;
        }
        unsigned long long m = __ballot(suf >= rem);
        int L = (m == 0) ? 0 : (63 - __clzll(m));
        uint32_t cum_above = (L < 63) ? __shfl(suf, L + 1) : 0u;

        uint32_t binv = (lane < 32) ? hh[L * 32 + lane] : 0u;
        uint32_t suf2 = binv;
        #pragma unroll
        for (int off = 1; off < 32; off <<= 1) {
            uint32_t t = __shfl_down(suf2, off);
            if (lane + off < 32) suf2 += t;
        }
        unsigned long long m2 = __ballot(lane < 32 && (cum_above + suf2) >= rem);
        int j = (m2 == 0) ? 0 : (63 - __clzll(m2));
        uint32_t above2 = cum_above + ((j < 31) ? __shfl(suf2, j + 1) : 0u);
        if (lane == 0) {
            res[0] = (uint32_t)(L * 32 + j);
            res[1] = rem - above2;
        }
    }
    __syncthreads();
}

// Grid = B*tilesPB blocks. Each block: one argmax tile; the LAST finisher per batch
// (atomic counter) runs the full select for that batch. No spinning anywhere.
__global__ __launch_bounds__(TPW) void fused_kernel(
    const float* __restrict__ probs, const float* __restrict__ anchors,
    const float* __restrict__ offsets, const float* __restrict__ window,
    float* __restrict__ sc, int* __restrict__ cls, uint32_t* __restrict__ done,
    float* __restrict__ out, int N, int B, int tilesPB)
{
    __shared__ __attribute__((aligned(16))) char smem[ROWS * 81 * 4];  // union: tile | (hh+cand)
    __shared__ uint32_t res[2];
    __shared__ uint32_t sh_vA, sh_remA, sh_cnt, sh_sel;

    float*    tile = (float*)smem;
    uint32_t* hh   = (uint32_t*)smem;                 // 8 KB
    uint64_t* cand = (uint64_t*)(smem + 8192);        // 16 KB

    const int tid  = threadIdx.x;
    const int lane = tid & 63;
    const int wk   = blockIdx.x;
    const int bb   = wk % B;
    const int t    = wk / B;

    // ================= WORKER: one 128-row argmax tile =================
    const int r0l = t * ROWS;
    const int rows_here = min(ROWS, N - r0l);
    const size_t r0 = (size_t)bb * N + r0l;

    if (rows_here > 0) {
        const float4* src = reinterpret_cast<const float4*>(probs + r0 * 80);
        const int nf4 = rows_here * 20;
        for (int f = tid; f < nf4; f += TPW) {
            float4 v = src[f];
            int fo = f * 4, row = fo / 80, col = fo - row * 80;
            float* dst = &tile[row * 81 + col];
            dst[0] = v.x; dst[1] = v.y; dst[2] = v.z; dst[3] = v.w;
        }
        __syncthreads();
        const int row = tid >> 2, g = tid & 3;        // 4 lanes per row, 20 cols each
        if (row < rows_here) {
            const float* rp = &tile[row * 81 + g * 20];
            float bv = rp[0]; int bc = g * 20;
            #pragma unroll
            for (int j = 1; j < 20; ++j) {
                float v = rp[j];
                if (v > bv) { bv = v; bc = g * 20 + j; }          // first-max in segment
            }
            #pragma unroll
            for (int off = 2; off >= 1; off >>= 1) {              // first-max across segments
                float ov = __shfl_down(bv, off);
                int   oc = __shfl_down(bc, off);
                if ((g + off) < 4 && (ov > bv || (ov == bv && oc < bc))) { bv = ov; bc = oc; }
            }
            if (g == 0) { sc[r0 + row] = bv; cls[r0 + row] = bc; }
        }
    }
    __threadfence();                                  // release sc/cls (all threads)
    __syncthreads();
    if (tid == 0) {
        uint32_t old = atomicAdd(&done[bb], 1u);
        sh_sel = (old == (uint32_t)(tilesPB - 1)) ? 1u : 0u;
    }
    __syncthreads();
    if (!sh_sel) return;

    // ================= SELECTOR (last finisher): per-batch top-K =================
    __threadfence();                                  // acquire sc/cls
    const float* sbase = sc + (size_t)bb * N;
    const float4* s4 = reinterpret_cast<const float4*>(sbase);
    const int n4 = N >> 2;

    // ---- pass-A histogram (bits[31:21]) with one-round wave aggregation (verified R22)
    for (int i = tid; i < 2048; i += TPW) hh[i] = 0u;
    if (tid == 0) sh_cnt = 0u;
    __syncthreads();
    for (int base = 0; base < n4; base += TPW) {
        const int f = base + tid;
        const bool act = (f < n4);
        float4 v = act ? s4[f] : make_float4(0.f, 0.f, 0.f, 0.f);
        #pragma unroll
        for (int j = 0; j < 4; ++j) {
            uint32_t bits = __float_as_uint(j==0 ? v.x : j==1 ? v.y : j==2 ? v.z : v.w);
            uint32_t bin  = bits >> SH_A;
            unsigned long long actm = __ballot(act);
            if (actm) {
                int ldr = __ffsll(actm) - 1;
                uint32_t b0 = __shfl(bin, ldr);
                unsigned long long eq = __ballot(act && bin == b0);
                if (lane == ldr) atomicAdd(&hh[b0], (uint32_t)__popcll(eq));
                if (act && bin != b0) atomicAdd(&hh[bin], 1u);
            }
        }
    }
    for (int i = (n4 << 2) + tid; i < N; i += TPW)
        atomicAdd(&hh[__float_as_uint(sbase[i]) >> SH_A], 1u);
    crossing2048(hh, KSEL, res);
    if (tid == 0) { sh_vA = res[0]; sh_remA = res[1]; }
    __syncthreads();
    const uint32_t vA = sh_vA, remA = sh_remA;

    // ---- pass-B histogram (bits[20:10]) over prefix-A matches
    for (int i = tid; i < 2048; i += TPW) hh[i] = 0u;
    __syncthreads();
    for (int f = tid; f < n4; f += TPW) {
        float4 v = s4[f];
        #pragma unroll
        for (int j = 0; j < 4; ++j) {
            uint32_t bits = __float_as_uint(j==0 ? v.x : j==1 ? v.y : j==2 ? v.z : v.w);
            if ((bits >> SH_A) == vA)
                atomicAdd(&hh[(bits >> SH_B) & 0x7FFu], 1u);
        }
    }
    for (int i = (n4 << 2) + tid; i < N; i += TPW) {
        uint32_t bits = __float_as_uint(sbase[i]);
        if ((bits >> SH_A) == vA) atomicAdd(&hh[(bits >> SH_B) & 0x7FFu], 1u);
    }
    crossing2048(hh, remA, res);
    const uint32_t t_lo = (vA << SH_A) | (res[0] << SH_B);

    // ---- gather candidates (wave-aggregated positions, verified R21)
    for (int i = tid; i < CAND_CAP; i += TPW) cand[i] = ~0ull;
    __syncthreads();
    for (int base = 0; base < n4; base += TPW) {
        const int f = base + tid;
        const bool act = (f < n4);
        float4 v = act ? s4[f] : make_float4(0.f, 0.f, 0.f, 0.f);
        #pragma unroll
        for (int j = 0; j < 4; ++j) {
            uint32_t bits = __float_as_uint(j==0 ? v.x : j==1 ? v.y : j==2 ? v.z : v.w);
            bool hit = act && (bits >= t_lo);
            unsigned long long m = __ballot(hit);
            if (m) {
                int ldr = __ffsll(m) - 1;
                uint32_t pbase = 0;
                if (lane == ldr) pbase = atomicAdd(&sh_cnt, (uint32_t)__popcll(m));
                pbase = __shfl(pbase, ldr);
                if (hit) {
                    uint32_t pos = pbase + (uint32_t)__popcll(m & ((1ull << lane) - 1ull));
                    if (pos < CAND_CAP)
                        cand[pos] = ((uint64_t)(~bits) << 32) | (uint64_t)(uint32_t)(4*f + j);
                }
            }
        }
    }
    for (int i = (n4 << 2) + tid; i < N; i += TPW) {
        uint32_t bits = __float_as_uint(sbase[i]);
        if (bits >= t_lo) {
            uint32_t pos = atomicAdd(&sh_cnt, 1u);
            if (pos < CAND_CAP)
                cand[pos] = ((uint64_t)(~bits) << 32) | (uint64_t)(uint32_t)i;
        }
    }
    __syncthreads();
    uint32_t G = sh_cnt;
    if (G > CAND_CAP) G = CAND_CAP;

    // ---- bitonic sort ascending: (~bits, idx) => score desc, idx asc (verified R21)
    for (unsigned k = 2; k <= CAND_CAP; k <<= 1) {
        for (unsigned j = k >> 1; j > 0; j >>= 1) {
            for (unsigned i = tid; i < CAND_CAP; i += TPW) {
                unsigned ixj = i ^ j;
                if (ixj > i) {
                    uint64_t a = cand[i], c2 = cand[ixj];
                    bool up = ((i & k) == 0);
                    if ((a > c2) == up) { cand[i] = c2; cand[ixj] = a; }
                }
            }
            __syncthreads();
        }
    }

    // ---- decode + write: sorted position IS the rank (verified)
    const float wy1 = window[0], wx1 = window[1], wy2 = window[2], wx2 = window[3];
    const int BK = B * KSEL;
    float* o_ai = out;             // [B,K,2] (b, idx)
    float* o_bx = out + 2 * BK;    // [B,K,4]
    float* o_cl = out + 6 * BK;
    float* o_sc = out + 7 * BK;
    float* o_vd = out + 8 * BK;

    const uint32_t W = (G < KSEL) ? G : KSEL;
    for (uint32_t r = tid; r < W; r += TPW) {
        const uint64_t kc = cand[r];
        if (kc == ~0ull) continue;

        uint32_t idx   = (uint32_t)kc;
        uint32_t sbits = ~(uint32_t)(kc >> 32);
        float score    = __uint_as_float(sbits);

        size_t base = (size_t)bb * N + idx;
        const float4 a = *reinterpret_cast<const float4*>(anchors + base * 4);
        const float4 o = *reinterpret_cast<const float4*>(offsets + base * 4);

        float h  = a.z - a.x;
        float w  = a.w - a.y;
        float cy = a.x + 0.5f * h + o.x * h;
        float cx = a.y + 0.5f * w + o.y * w;
        float hh2 = h * expf(o.z);
        float ww  = w * expf(o.w);
        float y1 = fminf(fmaxf(cy - 0.5f * hh2, wy1), wy2);
        float x1 = fminf(fmaxf(cx - 0.5f * ww,  wx1), wx2);
        float y2 = fminf(fmaxf(cy + 0.5f * hh2, wy1), wy2);
        float x2 = fminf(fmaxf(cx + 0.5f * ww,  wx1), wx2);

        int ok = bb * KSEL + (int)r;
        o_ai[ok*2 + 0] = (float)bb;
        o_ai[ok*2 + 1] = (float)idx;
        o_bx[ok*4 + 0] = y1;
        o_bx[ok*4 + 1] = x1;
        o_bx[ok*4 + 2] = y2;
        o_bx[ok*4 + 3] = x2;
        o_cl[ok] = (float)cls[base];
        o_sc[ok] = score;
        o_vd[ok] = (score > CONF_T) ? 1.0f : 0.0f;
    }
}

extern "C" void kernel_launch(void* const* d_in, const int* in_sizes, int n_in,
                              void* d_out, int out_size, void* d_ws, size_t ws_size,
                              hipStream_t stream)
{
    const float* anchors = (const float*)d_in[0];
    const float* probs   = (const float*)d_in[1];
    const float* offsets = (const float*)d_in[2];
    const float* window  = (const float*)d_in[3];

    const int B = out_size / (9 * KSEL);
    const int N = in_sizes[0] / (B * 4);
    const int total = B * N;
    const int tilesPB = (N + ROWS - 1) / ROWS;

    float*    sc   = (float*)d_ws;
    int*      cls  = (int*)((char*)d_ws + (size_t)total * 4);
    uint32_t* done = (uint32_t*)((char*)d_ws + (size_t)total * 8);

    hipLaunchKernelGGL(zero_done_kernel, dim3(1), dim3(64), 0, stream, done, B);

    hipLaunchKernelGGL(fused_kernel, dim3(B * tilesPB), dim3(TPW), 0, stream,
                       probs, anchors, offsets, window,
                       sc, cls, done, (float*)d_out, N, B, tilesPB);
}

// Round 25
// 152.835 us; speedup vs baseline: 5.9047x; 3.3833x over previous
//
#include <hip/hip_runtime.h>
#include <stdint.h>

#define CONF_T 0.05f
#define KSEL 1000
#define CAND_CAP 2048
#define ROWS 128
#define TPW 512
#define SH_A 21
#define SH_B 10

__global__ __launch_bounds__(64) void zero_done_kernel(uint32_t* __restrict__ done, int B)
{
    if ((int)threadIdx.x < B) done[threadIdx.x] = 0u;
}

// ---- wave-parallel crossing over 2048 LDS bins (verified R19-R24) ----
__device__ __forceinline__ void crossing2048(
    const uint32_t* __restrict__ hh, uint32_t rem, volatile uint32_t* __restrict__ res)
{
    __syncthreads();
    if (threadIdx.x < 64) {
        const int lane = threadIdx.x;
        uint32_t s = 0;
        #pragma unroll 8
        for (int j = 0; j < 32; ++j) s += hh[lane * 32 + j];
        uint32_t suf = s;
        #pragma unroll
        for (int off = 1; off < 64; off <<= 1) {
            uint32_t t = __shfl_down(suf, off);
            if (lane + off < 64) suf += t;
        }
        unsigned long long m = __ballot(suf >= rem);
        int L = (m == 0) ? 0 : (63 - __clzll(m));
        uint32_t cum_above = (L < 63) ? __shfl(suf, L + 1) : 0u;

        uint32_t binv = (lane < 32) ? hh[L * 32 + lane] : 0u;
        uint32_t suf2 = binv;
        #pragma unroll
        for (int off = 1; off < 32; off <<= 1) {
            uint32_t t = __shfl_down(suf2, off);
            if (lane + off < 32) suf2 += t;
        }
        unsigned long long m2 = __ballot(lane < 32 && (cum_above + suf2) >= rem);
        int j = (m2 == 0) ? 0 : (63 - __clzll(m2));
        uint32_t above2 = cum_above + ((j < 31) ? __shfl(suf2, j + 1) : 0u);
        if (lane == 0) {
            res[0] = (uint32_t)(L * 32 + j);
            res[1] = rem - above2;
        }
    }
    __syncthreads();
}

// Grid = B*tilesPB. Worker: one argmax tile, results published via device-scope
// atomicExch (coherence point, NO fences). Last finisher per batch runs the select.
__global__ __launch_bounds__(TPW) void fused_kernel(
    const float* __restrict__ probs, const float* __restrict__ anchors,
    const float* __restrict__ offsets, const float* __restrict__ window,
    unsigned long long* __restrict__ scpack, uint32_t* __restrict__ done,
    float* __restrict__ out, int N, int B, int tilesPB)
{
    __shared__ __attribute__((aligned(16))) char smem[ROWS * 81 * 4];
    __shared__ uint32_t res[2];
    __shared__ uint32_t sh_vA, sh_remA, sh_cnt, sh_sel;

    float*    tile = (float*)smem;
    uint32_t* hh   = (uint32_t*)smem;                 // 8 KB
    uint64_t* cand = (uint64_t*)(smem + 8192);        // 16 KB

    const int tid  = threadIdx.x;
    const int lane = tid & 63;
    const int wk   = blockIdx.x;
    const int bb   = wk % B;
    const int t    = wk / B;

    // ================= WORKER: one 128-row argmax tile =================
    const int r0l = t * ROWS;
    const int rows_here = min(ROWS, N - r0l);
    const size_t r0 = (size_t)bb * N + r0l;

    if (rows_here > 0) {
        const float4* src = reinterpret_cast<const float4*>(probs + r0 * 80);
        const int nf4 = rows_here * 20;
        for (int f = tid; f < nf4; f += TPW) {
            float4 v = src[f];
            int fo = f * 4, row = fo / 80, col = fo - row * 80;
            float* dst = &tile[row * 81 + col];
            dst[0] = v.x; dst[1] = v.y; dst[2] = v.z; dst[3] = v.w;
        }
        __syncthreads();
        const int row = tid >> 2, g = tid & 3;        // 4 lanes per row
        if (row < rows_here) {
            const float* rp = &tile[row * 81 + g * 20];
            float bv = rp[0]; int bc = g * 20;
            #pragma unroll
            for (int j = 1; j < 20; ++j) {
                float v = rp[j];
                if (v > bv) { bv = v; bc = g * 20 + j; }          // first-max in segment
            }
            #pragma unroll
            for (int off = 2; off >= 1; off >>= 1) {              // first-max across segments
                float ov = __shfl_down(bv, off);
                int   oc = __shfl_down(bc, off);
                if ((g + off) < 4 && (ov > bv || (ov == bv && oc < bc))) { bv = ov; bc = oc; }
            }
            if (g == 0) {
                unsigned long long pk =
                    ((unsigned long long)__float_as_uint(bv) << 32) | (uint32_t)bc;
                atomicExch(&scpack[r0 + row], pk);     // device-scope: lands at coherence point
            }
        }
    }
    __syncthreads();                                   // drains vmcnt: exchanges complete
    if (tid == 0) {
        uint32_t old = atomicAdd(&done[bb], 1u);
        sh_sel = (old == (uint32_t)(tilesPB - 1)) ? 1u : 0u;
    }
    __syncthreads();
    if (!sh_sel) return;

    // ================= SELECTOR (last finisher): per-batch top-K =================
    const unsigned long long* sbase = scpack + (size_t)bb * N;
    const ulonglong2* s2 = reinterpret_cast<const ulonglong2*>(sbase);
    const int n2 = N >> 1;

    // ---- pass-A histogram (bits[31:21]), one-round wave aggregation (verified R22)
    for (int i = tid; i < 2048; i += TPW) hh[i] = 0u;
    if (tid == 0) sh_cnt = 0u;
    __syncthreads();
    for (int base = 0; base < n2; base += TPW) {
        const int f = base + tid;
        const bool act = (f < n2);
        ulonglong2 v;
        v.x = act ? s2[f].x : 0ull; v.y = act ? s2[f].y : 0ull;
        #pragma unroll
        for (int j = 0; j < 2; ++j) {
            uint32_t bits = (uint32_t)((j == 0 ? v.x : v.y) >> 32);
            uint32_t bin  = bits >> SH_A;
            unsigned long long actm = __ballot(act);
            if (actm) {
                int ldr = __ffsll(actm) - 1;
                uint32_t b0 = __shfl(bin, ldr);
                unsigned long long eq = __ballot(act && bin == b0);
                if (lane == ldr) atomicAdd(&hh[b0], (uint32_t)__popcll(eq));
                if (act && bin != b0) atomicAdd(&hh[bin], 1u);
            }
        }
    }
    for (int i = (n2 << 1) + tid; i < N; i += TPW)
        atomicAdd(&hh[(uint32_t)(sbase[i] >> 32) >> SH_A], 1u);
    crossing2048(hh, KSEL, res);
    if (tid == 0) { sh_vA = res[0]; sh_remA = res[1]; }
    __syncthreads();
    const uint32_t vA = sh_vA, remA = sh_remA;

    // ---- pass-B histogram (bits[20:10]) over prefix-A matches
    for (int i = tid; i < 2048; i += TPW) hh[i] = 0u;
    __syncthreads();
    for (int f = tid; f < n2; f += TPW) {
        ulonglong2 v = s2[f];
        #pragma unroll
        for (int j = 0; j < 2; ++j) {
            uint32_t bits = (uint32_t)((j == 0 ? v.x : v.y) >> 32);
            if ((bits >> SH_A) == vA)
                atomicAdd(&hh[(bits >> SH_B) & 0x7FFu], 1u);
        }
    }
    for (int i = (n2 << 1) + tid; i < N; i += TPW) {
        uint32_t bits = (uint32_t)(sbase[i] >> 32);
        if ((bits >> SH_A) == vA) atomicAdd(&hh[(bits >> SH_B) & 0x7FFu], 1u);
    }
    crossing2048(hh, remA, res);
    const uint32_t t_lo = (vA << SH_A) | (res[0] << SH_B);

    // ---- gather candidates (wave-aggregated positions, verified R21)
    for (int i = tid; i < CAND_CAP; i += TPW) cand[i] = ~0ull;
    __syncthreads();
    for (int base = 0; base < n2; base += TPW) {
        const int f = base + tid;
        const bool act = (f < n2);
        ulonglong2 v;
        v.x = act ? s2[f].x : 0ull; v.y = act ? s2[f].y : 0ull;
        #pragma unroll
        for (int j = 0; j < 2; ++j) {
            uint32_t bits = (uint32_t)((j == 0 ? v.x : v.y) >> 32);
            bool hit = act && (bits >= t_lo);
            unsigned long long m = __ballot(hit);
            if (m) {
                int ldr = __ffsll(m) - 1;
                uint32_t pbase = 0;
                if (lane == ldr) pbase = atomicAdd(&sh_cnt, (uint32_t)__popcll(m));
                pbase = __shfl(pbase, ldr);
                if (hit) {
                    uint32_t pos = pbase + (uint32_t)__popcll(m & ((1ull << lane) - 1ull));
                    if (pos < CAND_CAP)
                        cand[pos] = ((uint64_t)(~bits) << 32) | (uint64_t)(uint32_t)(2*f + j);
                }
            }
        }
    }
    for (int i = (n2 << 1) + tid; i < N; i += TPW) {
        uint32_t bits = (uint32_t)(sbase[i] >> 32);
        if (bits >= t_lo) {
            uint32_t pos = atomicAdd(&sh_cnt, 1u);
            if (pos < CAND_CAP)
                cand[pos] = ((uint64_t)(~bits) << 32) | (uint64_t)(uint32_t)i;
        }
    }
    __syncthreads();
    uint32_t G = sh_cnt;
    if (G > CAND_CAP) G = CAND_CAP;

    // ---- bitonic sort ascending: (~bits, idx) => score desc, idx asc (verified R21)
    for (unsigned k = 2; k <= CAND_CAP; k <<= 1) {
        for (unsigned j = k >> 1; j > 0; j >>= 1) {
            for (unsigned i = tid; i < CAND_CAP; i += TPW) {
                unsigned ixj = i ^ j;
                if (ixj > i) {
                    uint64_t a = cand[i], c2 = cand[ixj];
                    bool up = ((i & k) == 0);
                    if ((a > c2) == up) { cand[i] = c2; cand[ixj] = a; }
                }
            }
            __syncthreads();
        }
    }

    // ---- decode + write: sorted position IS the rank (verified)
    const float wy1 = window[0], wx1 = window[1], wy2 = window[2], wx2 = window[3];
    const int BK = B * KSEL;
    float* o_ai = out;             // [B,K,2] (b, idx)
    float* o_bx = out + 2 * BK;    // [B,K,4]
    float* o_cl = out + 6 * BK;
    float* o_sc = out + 7 * BK;
    float* o_vd = out + 8 * BK;

    const uint32_t W = (G < KSEL) ? G : KSEL;
    for (uint32_t r = tid; r < W; r += TPW) {
        const uint64_t kc = cand[r];
        if (kc == ~0ull) continue;

        uint32_t idx   = (uint32_t)kc;
        uint32_t sbits = ~(uint32_t)(kc >> 32);
        float score    = __uint_as_float(sbits);

        size_t base = (size_t)bb * N + idx;
        const float4 a = *reinterpret_cast<const float4*>(anchors + base * 4);
        const float4 o = *reinterpret_cast<const float4*>(offsets + base * 4);

        float h  = a.z - a.x;
        float w  = a.w - a.y;
        float cy = a.x + 0.5f * h + o.x * h;
        float cx = a.y + 0.5f * w + o.y * w;
        float hh2 = h * expf(o.z);
        float ww  = w * expf(o.w);
        float y1 = fminf(fmaxf(cy - 0.5f * hh2, wy1), wy2);
        float x1 = fminf(fmaxf(cx - 0.5f * ww,  wx1), wx2);
        float y2 = fminf(fmaxf(cy + 0.5f * hh2, wy1), wy2);
        float x2 = fminf(fmaxf(cx + 0.5f * ww,  wx1), wx2);

        int ok = bb * KSEL + (int)r;
        o_ai[ok*2 + 0] = (float)bb;
        o_ai[ok*2 + 1] = (float)idx;
        o_bx[ok*4 + 0] = y1;
        o_bx[ok*4 + 1] = x1;
        o_bx[ok*4 + 2] = y2;
        o_bx[ok*4 + 3] = x2;
        o_cl[ok] = (float)(uint32_t)(scpack[base] & 0xFFFFFFFFull);
        o_sc[ok] = score;
        o_vd[ok] = (score > CONF_T) ? 1.0f : 0.0f;
    }
}

extern "C" void kernel_launch(void* const* d_in, const int* in_sizes, int n_in,
                              void* d_out, int out_size, void* d_ws, size_t ws_size,
                              hipStream_t stream)
{
    const float* anchors = (const float*)d_in[0];
    const float* probs   = (const float*)d_in[1];
    const float* offsets = (const float*)d_in[2];
    const float* window  = (const float*)d_in[3];

    const int B = out_size / (9 * KSEL);
    const int N = in_sizes[0] / (B * 4);
    const int total = B * N;
    const int tilesPB = (N + ROWS - 1) / ROWS;

    unsigned long long* scpack = (unsigned long long*)d_ws;
    uint32_t*           done   = (uint32_t*)((char*)d_ws + (size_t)total * 8);

    hipLaunchKernelGGL(zero_done_kernel, dim3(1), dim3(64), 0, stream, done, B);

    hipLaunchKernelGGL(fused_kernel, dim3(B * tilesPB), dim3(TPW), 0, stream,
                       probs, anchors, offsets, window,
                       scpack, done, (float*)d_out, N, B, tilesPB);
}

// Round 27
// 86.189 us; speedup vs baseline: 10.4705x; 1.7733x over previous
//
#include <hip/hip_runtime.h>
#include <stdint.h>

#define CONF_T 0.05f
#define KSEL 1000
#define CAND_CAP 2048
#define ROWS 128
#define T1 256
#define SH_A 21
#define SH_B 10

// ---------------- Kernel 1: LDS-staged coalesced argmax (verified R22) ----------------
__global__ __launch_bounds__(T1) void score_argmax_kernel(
    const float* __restrict__ probs, float* __restrict__ sc, int* __restrict__ cls,
    int total)
{
    __shared__ float tile[ROWS * 81];
    const int r0  = blockIdx.x * ROWS;
    const int tid = threadIdx.x;
    const int rows_here = min(ROWS, total - r0);

    const float4* src = reinterpret_cast<const float4*>(probs + (size_t)r0 * 80);
    const int nf4 = rows_here * 20;
    for (int f = tid; f < nf4; f += T1) {
        float4 v = src[f];
        int fo  = f * 4;
        int row = fo / 80;
        int col = fo - row * 80;
        float* dst = &tile[row * 81 + col];
        dst[0] = v.x; dst[1] = v.y; dst[2] = v.z; dst[3] = v.w;
    }
    __syncthreads();

    if (tid < rows_here) {
        const float* row = &tile[tid * 81];
        float best = row[0]; int bc = 0;
        #pragma unroll
        for (int j = 1; j < 80; ++j) {
            float v = row[j];
            if (v > best) { best = v; bc = j; }
        }
        sc[r0 + tid]  = best;
        cls[r0 + tid] = bc;
    }
}

// ---- wave-parallel crossing over 2048 LDS bins (verified) ----
__device__ __forceinline__ void crossing2048(
    const uint32_t* __restrict__ hh, uint32_t rem, volatile uint32_t* __restrict__ res)
{
    __syncthreads();
    if (threadIdx.x < 64) {
        const int lane = threadIdx.x;
        uint32_t s = 0;
        #pragma unroll 8
        for (int j = 0; j < 32; ++j) s += hh[lane * 32 + j];
        uint32_t suf = s;
        #pragma unroll
        for (int off = 1; off < 64; off <<= 1) {
            uint32_t t = __shfl_down(suf, off);
            if (lane + off < 64) suf += t;
        }
        unsigned long long m = __ballot(suf >= rem);
        int L = (m == 0) ? 0 : (63 - __clzll(m));
        uint32_t cum_above = (L < 63) ? __shfl(suf, L + 1) : 0u;

        uint32_t binv = (lane < 32) ? hh[L * 32 + lane] : 0u;
        uint32_t suf2 = binv;
        #pragma unroll
        for (int off = 1; off < 32; off <<= 1) {
            uint32_t t = __shfl_down(suf2, off);
            if (lane + off < 32) suf2 += t;
        }
        unsigned long long m2 = __ballot(lane < 32 && (cum_above + suf2) >= rem);
        int j = (m2 == 0) ? 0 : (63 - __clzll(m2));
        uint32_t above2 = cum_above + ((j < 31) ? __shfl(suf2, j + 1) : 0u);
        if (lane == 0) {
            res[0] = (uint32_t)(L * 32 + j);
            res[1] = rem - above2;
        }
    }
    __syncthreads();
}

// ---------------- Kernel 2: select with u32-packed-key sort (u64 fallback) ------------
__global__ __launch_bounds__(1024) void final_select_kernel(
    const float* __restrict__ scores, const int* __restrict__ cls_ws,
    const float* __restrict__ anchors, const float* __restrict__ offsets,
    const float* __restrict__ window, float* __restrict__ out,
    int N, int B)
{
    const int b    = blockIdx.x;
    const int tid  = threadIdx.x;
    const int lane = tid & 63;

    __shared__ uint32_t hh[2048];
    __shared__ uint32_t res[2];
    __shared__ uint32_t sh_vA, sh_remA, sh_cnt, sh_maxbits;
    __shared__ uint64_t cand[CAND_CAP];              // u64 fallback buffer
    uint32_t* cand32 = (uint32_t*)cand;              // u32 fast-path buffer (aliased)

    const float* sbase = scores + (size_t)b * N;
    const float4* s4 = reinterpret_cast<const float4*>(sbase);
    const int n4 = N >> 2;

    // ---- pass-A histogram (bits[31:21]) with one-round wave aggregation (verified)
    for (int i = tid; i < 2048; i += 1024) hh[i] = 0u;
    if (tid == 0) sh_cnt = 0u;
    __syncthreads();
    for (int base = 0; base < n4; base += 1024) {
        const int f = base + tid;
        const bool act = (f < n4);
        float4 v = act ? s4[f] : make_float4(0.f, 0.f, 0.f, 0.f);
        #pragma unroll
        for (int j = 0; j < 4; ++j) {
            uint32_t bits = __float_as_uint(j==0 ? v.x : j==1 ? v.y : j==2 ? v.z : v.w);
            uint32_t bin  = bits >> SH_A;
            unsigned long long actm = __ballot(act);
            if (actm) {
                int ldr = __ffsll(actm) - 1;
                uint32_t b0 = __shfl(bin, ldr);
                unsigned long long eq = __ballot(act && bin == b0);
                if (lane == ldr) atomicAdd(&hh[b0], (uint32_t)__popcll(eq));
                if (act && bin != b0) atomicAdd(&hh[bin], 1u);
            }
        }
    }
    crossing2048(hh, KSEL, res);
    if (tid == 0) { sh_vA = res[0]; sh_remA = res[1]; }
    __syncthreads();
    const uint32_t vA = sh_vA, remA = sh_remA;

    // ---- pass-B histogram (bits[20:10]) over prefix-A matches (verified)
    for (int i = tid; i < 2048; i += 1024) hh[i] = 0u;
    __syncthreads();
    for (int f = tid; f < n4; f += 1024) {
        float4 v = s4[f];
        #pragma unroll
        for (int j = 0; j < 4; ++j) {
            uint32_t bits = __float_as_uint(j==0 ? v.x : j==1 ? v.y : j==2 ? v.z : v.w);
            if ((bits >> SH_A) == vA)
                atomicAdd(&hh[(bits >> SH_B) & 0x7FFu], 1u);
        }
    }
    crossing2048(hh, remA, res);
    const uint32_t t_lo = (vA << SH_A) | (res[0] << SH_B);

    // ---- gather candidate (bits, idx) pairs into cand as u64 (+ track max bits)
    for (int i = tid; i < CAND_CAP; i += 1024) cand[i] = ~0ull;
    if (tid == 0) sh_maxbits = t_lo;
    __syncthreads();
    for (int base = 0; base < n4; base += 1024) {
        const int f = base + tid;
        const bool act = (f < n4);
        float4 v = act ? s4[f] : make_float4(0.f, 0.f, 0.f, 0.f);
        #pragma unroll
        for (int j = 0; j < 4; ++j) {
            uint32_t bits = __float_as_uint(j==0 ? v.x : j==1 ? v.y : j==2 ? v.z : v.w);
            bool hit = act && (bits >= t_lo);
            unsigned long long m = __ballot(hit);
            if (m) {
                int ldr = __ffsll(m) - 1;
                uint32_t pbase = 0;
                if (lane == ldr) pbase = atomicAdd(&sh_cnt, (uint32_t)__popcll(m));
                pbase = __shfl(pbase, ldr);
                if (hit) {
                    uint32_t pos = pbase + (uint32_t)__popcll(m & ((1ull << lane) - 1ull));
                    if (pos < CAND_CAP)
                        cand[pos] = ((uint64_t)(~bits) << 32) | (uint64_t)(uint32_t)(4*f + j);
                    atomicMax(&sh_maxbits, bits);
                }
            }
        }
    }
    __syncthreads();
    uint32_t G = sh_cnt;
    if (G > CAND_CAP) G = CAND_CAP;
    const uint32_t maxbits = sh_maxbits;
    const bool pack32 = ((maxbits - t_lo) <= 0xFFFFu) && (N <= 65500);

    if (pack32) {
        // ---- repack candidates to u32: key = (maxbits - bits)<<16 | idx
        // ascending => score desc, idx asc. Real keys can't be 0xFFFFFFFF (idx < N < 65500).
        uint32_t k0 = 0xFFFFFFFFu, k1 = 0xFFFFFFFFu;
        {
            const int i0 = tid, i1 = tid + 1024;
            uint64_t c0 = cand[i0], c1 = cand[i1];
            if (c0 != ~0ull) {
                uint32_t bits = ~(uint32_t)(c0 >> 32);
                k0 = ((maxbits - bits) << 16) | ((uint32_t)c0 & 0xFFFFu);
            }
            if (c1 != ~0ull) {
                uint32_t bits = ~(uint32_t)(c1 >> 32);
                k1 = ((maxbits - bits) << 16) | ((uint32_t)c1 & 0xFFFFu);
            }
        }
        __syncthreads();
        cand32[tid] = k0; cand32[tid + 1024] = k1;
        __syncthreads();

        // ---- bitonic sort on u32 keys (same network as verified u64 version)
        for (unsigned k = 2; k <= CAND_CAP; k <<= 1) {
            for (unsigned j = k >> 1; j > 0; j >>= 1) {
                for (unsigned i = tid; i < CAND_CAP; i += 1024) {
                    unsigned ixj = i ^ j;
                    if (ixj > i) {
                        uint32_t a = cand32[i], c2 = cand32[ixj];
                        bool up = ((i & k) == 0);
                        if ((a > c2) == up) { cand32[i] = c2; cand32[ixj] = a; }
                    }
                }
                __syncthreads();
            }
        }
    } else {
        // ---- u64 bitonic fallback (verified R21)
        for (unsigned k = 2; k <= CAND_CAP; k <<= 1) {
            for (unsigned j = k >> 1; j > 0; j >>= 1) {
                for (unsigned i = tid; i < CAND_CAP; i += 1024) {
                    unsigned ixj = i ^ j;
                    if (ixj > i) {
                        uint64_t a = cand[i], c2 = cand[ixj];
                        bool up = ((i & k) == 0);
                        if ((a > c2) == up) { cand[i] = c2; cand[ixj] = a; }
                    }
                }
                __syncthreads();
            }
        }
    }

    // ---- decode + write: sorted position IS the rank (verified)
    const float wy1 = window[0], wx1 = window[1], wy2 = window[2], wx2 = window[3];
    const int BK = B * KSEL;
    float* o_ai = out;             // [B,K,2] (b, idx)
    float* o_bx = out + 2 * BK;    // [B,K,4]
    float* o_cl = out + 6 * BK;
    float* o_sc = out + 7 * BK;
    float* o_vd = out + 8 * BK;

    const uint32_t W = (G < KSEL) ? G : KSEL;
    for (uint32_t r = tid; r < W; r += 1024) {
        uint32_t idx, sbits;
        if (pack32) {
            uint32_t kk = cand32[r];
            if (kk == 0xFFFFFFFFu) continue;
            idx   = kk & 0xFFFFu;
            sbits = maxbits - (kk >> 16);
        } else {
            uint64_t kc = cand[r];
            if (kc == ~0ull) continue;
            idx   = (uint32_t)kc;
            sbits = ~(uint32_t)(kc >> 32);
        }
        float score = __uint_as_float(sbits);

        size_t base = (size_t)b * N + idx;
        const float4 a = *reinterpret_cast<const float4*>(anchors + base * 4);
        const float4 o = *reinterpret_cast<const float4*>(offsets + base * 4);

        float h  = a.z - a.x;
        float w  = a.w - a.y;
        float cy = a.x + 0.5f * h + o.x * h;
        float cx = a.y + 0.5f * w + o.y * w;
        float hh2 = h * expf(o.z);
        float ww  = w * expf(o.w);
        float y1 = fminf(fmaxf(cy - 0.5f * hh2, wy1), wy2);
        float x1 = fminf(fmaxf(cx - 0.5f * ww,  wx1), wx2);
        float y2 = fminf(fmaxf(cy + 0.5f * hh2, wy1), wy2);
        float x2 = fminf(fmaxf(cx + 0.5f * ww,  wx1), wx2);

        int ok = b * KSEL + (int)r;
        o_ai[ok*2 + 0] = (float)b;
        o_ai[ok*2 + 1] = (float)idx;
        o_bx[ok*4 + 0] = y1;
        o_bx[ok*4 + 1] = x1;
        o_bx[ok*4 + 2] = y2;
        o_bx[ok*4 + 3] = x2;
        o_cl[ok] = (float)cls_ws[base];
        o_sc[ok] = score;
        o_vd[ok] = (score > CONF_T) ? 1.0f : 0.0f;
    }
}

extern "C" void kernel_launch(void* const* d_in, const int* in_sizes, int n_in,
                              void* d_out, int out_size, void* d_ws, size_t ws_size,
                              hipStream_t stream)
{
    const float* anchors = (const float*)d_in[0];
    const float* probs   = (const float*)d_in[1];
    const float* offsets = (const float*)d_in[2];
    const float* window  = (const float*)d_in[3];

    const int B = out_size / (9 * KSEL);
    const int N = in_sizes[0] / (B * 4);
    const int total = B * N;

    float* sc  = (float*)d_ws;
    int*   cls = (int*)((char*)d_ws + (size_t)total * 4);

    hipLaunchKernelGGL(score_argmax_kernel,
                       dim3((total + ROWS - 1) / ROWS), dim3(T1), 0, stream,
                       probs, sc, cls, total);

    hipLaunchKernelGGL(final_select_kernel, dim3(B), dim3(1024), 0, stream,
                       sc, cls, anchors, offsets, window,
                       (float*)d_out, N, B);
}

// Round 28
// 72.534 us; speedup vs baseline: 12.4416x; 1.1882x over previous
//
#include <hip/hip_runtime.h>
#include <stdint.h>

#define CONF_T 0.05f
#define KSEL 1000
#define CAND_CAP 2048
#define ROWS 128
#define T1 256
#define SH_A 21
#define SH_B 10

// ---------------- Kernel 1: LDS-staged coalesced argmax (verified R22) ----------------
__global__ __launch_bounds__(T1) void score_argmax_kernel(
    const float* __restrict__ probs, float* __restrict__ sc, int* __restrict__ cls,
    int total)
{
    __shared__ float tile[ROWS * 81];
    const int r0  = blockIdx.x * ROWS;
    const int tid = threadIdx.x;
    const int rows_here = min(ROWS, total - r0);

    const float4* src = reinterpret_cast<const float4*>(probs + (size_t)r0 * 80);
    const int nf4 = rows_here * 20;
    for (int f = tid; f < nf4; f += T1) {
        float4 v = src[f];
        int fo  = f * 4;
        int row = fo / 80;
        int col = fo - row * 80;
        float* dst = &tile[row * 81 + col];
        dst[0] = v.x; dst[1] = v.y; dst[2] = v.z; dst[3] = v.w;
    }
    __syncthreads();

    if (tid < rows_here) {
        const float* row = &tile[tid * 81];
        float best = row[0]; int bc = 0;
        #pragma unroll
        for (int j = 1; j < 80; ++j) {
            float v = row[j];
            if (v > best) { best = v; bc = j; }
        }
        sc[r0 + tid]  = best;
        cls[r0 + tid] = bc;
    }
}

// ---- wave-parallel crossing over 2048 LDS bins (verified) ----
__device__ __forceinline__ void crossing2048(
    const uint32_t* __restrict__ hh, uint32_t rem, volatile uint32_t* __restrict__ res)
{
    __syncthreads();
    if (threadIdx.x < 64) {
        const int lane = threadIdx.x;
        uint32_t s = 0;
        #pragma unroll 8
        for (int j = 0; j < 32; ++j) s += hh[lane * 32 + j];
        uint32_t suf = s;
        #pragma unroll
        for (int off = 1; off < 64; off <<= 1) {
            uint32_t t = __shfl_down(suf, off);
            if (lane + off < 64) suf += t;
        }
        unsigned long long m = __ballot(suf >= rem);
        int L = (m == 0) ? 0 : (63 - __clzll(m));
        uint32_t cum_above = (L < 63) ? __shfl(suf, L + 1) : 0u;

        uint32_t binv = (lane < 32) ? hh[L * 32 + lane] : 0u;
        uint32_t suf2 = binv;
        #pragma unroll
        for (int off = 1; off < 32; off <<= 1) {
            uint32_t t = __shfl_down(suf2, off);
            if (lane + off < 32) suf2 += t;
        }
        unsigned long long m2 = __ballot(lane < 32 && (cum_above + suf2) >= rem);
        int j = (m2 == 0) ? 0 : (63 - __clzll(m2));
        uint32_t above2 = cum_above + ((j < 31) ? __shfl(suf2, j + 1) : 0u);
        if (lane == 0) {
            res[0] = (uint32_t)(L * 32 + j);
            res[1] = rem - above2;
        }
    }
    __syncthreads();
}

__device__ __forceinline__ uint32_t u32min(uint32_t a, uint32_t b) { return a < b ? a : b; }
__device__ __forceinline__ uint32_t u32max(uint32_t a, uint32_t b) { return a > b ? a : b; }

// ---------------- Kernel 2: select; hybrid reg/shuffle bitonic on u32 keys ------------
__global__ __launch_bounds__(1024) void final_select_kernel(
    const float* __restrict__ scores, const int* __restrict__ cls_ws,
    const float* __restrict__ anchors, const float* __restrict__ offsets,
    const float* __restrict__ window, float* __restrict__ out,
    int N, int B)
{
    const int b    = blockIdx.x;
    const int tid  = threadIdx.x;
    const int lane = tid & 63;

    __shared__ uint32_t hh[2048];
    __shared__ uint32_t res[2];
    __shared__ uint32_t sh_vA, sh_remA, sh_cnt, sh_maxbits;
    __shared__ uint64_t cand[CAND_CAP];
    uint32_t* cand32 = (uint32_t*)cand;

    const float* sbase = scores + (size_t)b * N;
    const float4* s4 = reinterpret_cast<const float4*>(sbase);
    const int n4 = N >> 2;

    // ---- pass-A histogram (bits[31:21]) with one-round wave aggregation (verified)
    for (int i = tid; i < 2048; i += 1024) hh[i] = 0u;
    if (tid == 0) sh_cnt = 0u;
    __syncthreads();
    for (int base = 0; base < n4; base += 1024) {
        const int f = base + tid;
        const bool act = (f < n4);
        float4 v = act ? s4[f] : make_float4(0.f, 0.f, 0.f, 0.f);
        #pragma unroll
        for (int j = 0; j < 4; ++j) {
            uint32_t bits = __float_as_uint(j==0 ? v.x : j==1 ? v.y : j==2 ? v.z : v.w);
            uint32_t bin  = bits >> SH_A;
            unsigned long long actm = __ballot(act);
            if (actm) {
                int ldr = __ffsll(actm) - 1;
                uint32_t b0 = __shfl(bin, ldr);
                unsigned long long eq = __ballot(act && bin == b0);
                if (lane == ldr) atomicAdd(&hh[b0], (uint32_t)__popcll(eq));
                if (act && bin != b0) atomicAdd(&hh[bin], 1u);
            }
        }
    }
    crossing2048(hh, KSEL, res);
    if (tid == 0) { sh_vA = res[0]; sh_remA = res[1]; }
    __syncthreads();
    const uint32_t vA = sh_vA, remA = sh_remA;

    // ---- pass-B histogram (bits[20:10]) over prefix-A matches (verified)
    for (int i = tid; i < 2048; i += 1024) hh[i] = 0u;
    __syncthreads();
    for (int f = tid; f < n4; f += 1024) {
        float4 v = s4[f];
        #pragma unroll
        for (int j = 0; j < 4; ++j) {
            uint32_t bits = __float_as_uint(j==0 ? v.x : j==1 ? v.y : j==2 ? v.z : v.w);
            if ((bits >> SH_A) == vA)
                atomicAdd(&hh[(bits >> SH_B) & 0x7FFu], 1u);
        }
    }
    crossing2048(hh, remA, res);
    const uint32_t t_lo = (vA << SH_A) | (res[0] << SH_B);

    // ---- gather candidate (bits, idx) pairs as u64 (+ track max bits) (verified)
    for (int i = tid; i < CAND_CAP; i += 1024) cand[i] = ~0ull;
    if (tid == 0) sh_maxbits = t_lo;
    __syncthreads();
    for (int base = 0; base < n4; base += 1024) {
        const int f = base + tid;
        const bool act = (f < n4);
        float4 v = act ? s4[f] : make_float4(0.f, 0.f, 0.f, 0.f);
        #pragma unroll
        for (int j = 0; j < 4; ++j) {
            uint32_t bits = __float_as_uint(j==0 ? v.x : j==1 ? v.y : j==2 ? v.z : v.w);
            bool hit = act && (bits >= t_lo);
            unsigned long long m = __ballot(hit);
            if (m) {
                int ldr = __ffsll(m) - 1;
                uint32_t pbase = 0;
                if (lane == ldr) pbase = atomicAdd(&sh_cnt, (uint32_t)__popcll(m));
                pbase = __shfl(pbase, ldr);
                if (hit) {
                    uint32_t pos = pbase + (uint32_t)__popcll(m & ((1ull << lane) - 1ull));
                    if (pos < CAND_CAP)
                        cand[pos] = ((uint64_t)(~bits) << 32) | (uint64_t)(uint32_t)(4*f + j);
                    atomicMax(&sh_maxbits, bits);
                }
            }
        }
    }
    __syncthreads();
    uint32_t G = sh_cnt;
    if (G > CAND_CAP) G = CAND_CAP;
    const uint32_t maxbits = sh_maxbits;
    const bool pack32 = ((maxbits - t_lo) <= 0xFFFFu) && (N <= 65500);

    const float wy1 = window[0], wx1 = window[1], wy2 = window[2], wx2 = window[3];
    const int BK = B * KSEL;
    float* o_ai = out;             // [B,K,2] (b, idx)
    float* o_bx = out + 2 * BK;    // [B,K,4]
    float* o_cl = out + 6 * BK;
    float* o_sc = out + 7 * BK;
    float* o_vd = out + 8 * BK;
    const uint32_t W = (G < KSEL) ? G : KSEL;

    if (pack32) {
        // ---- pack to u32 keys directly into registers: key=(maxbits-bits)<<16|idx.
        // ascending => score desc, idx asc; pad 0xFFFFFFFF (> any real key).
        uint32_t x = 0xFFFFFFFFu, y = 0xFFFFFFFFu;
        {
            uint64_t c0 = cand[2*tid], c1 = cand[2*tid + 1];
            if (c0 != ~0ull) {
                uint32_t bits = ~(uint32_t)(c0 >> 32);
                x = ((maxbits - bits) << 16) | ((uint32_t)c0 & 0xFFFFu);
            }
            if (c1 != ~0ull) {
                uint32_t bits = ~(uint32_t)(c1 >> 32);
                y = ((maxbits - bits) << 16) | ((uint32_t)c1 & 0xFFFFu);
            }
        }
        __syncthreads();   // all cand reads done before any LDS-session write (aliasing)

        // ---- hybrid bitonic: thread t owns elems (2t, 2t+1); j<=64 via regs/shfl (no
        // barriers), j>=128 via LDS sessions (1 barrier/phase).
        for (unsigned k = 2; k <= CAND_CAP; k <<= 1) {
            unsigned j = k >> 1;
            const bool up = (((unsigned)(2 * tid) & k) == 0);
            if (j >= 128) {
                cand32[2*tid] = x; cand32[2*tid + 1] = y;
                __syncthreads();
                for (; j >= 128; j >>= 1) {
                    for (unsigned i = tid; i < CAND_CAP; i += 1024) {
                        unsigned ixj = i ^ j;
                        if (ixj > i) {
                            uint32_t a = cand32[i], c2 = cand32[ixj];
                            bool upi = ((i & k) == 0);
                            if ((a > c2) == upi) { cand32[i] = c2; cand32[ixj] = a; }
                        }
                    }
                    __syncthreads();
                }
                x = cand32[2*tid]; y = cand32[2*tid + 1];
                __syncthreads();   // reads complete before next session's writes
            }
            for (; j >= 2; j >>= 1) {
                const unsigned pm = j >> 1;            // partner lane mask (<= 32)
                uint32_t ox = (uint32_t)__shfl_xor((int)x, (int)pm);
                uint32_t oy = (uint32_t)__shfl_xor((int)y, (int)pm);
                const bool lower = ((tid & pm) == 0);
                const bool keepmin = (lower == up);
                x = keepmin ? u32min(x, ox) : u32max(x, ox);
                y = keepmin ? u32min(y, oy) : u32max(y, oy);
            }
            {   // j == 1: in-thread
                uint32_t mn = u32min(x, y), mx = u32max(x, y);
                x = up ? mn : mx;
                y = up ? mx : mn;
            }
        }

        // ---- decode from registers: thread t holds ranks 2t (x), 2t+1 (y)
        #pragma unroll
        for (int e = 0; e < 2; ++e) {
            uint32_t r  = 2 * tid + e;
            uint32_t kk = e ? y : x;
            if (r >= W || kk == 0xFFFFFFFFu) continue;
            uint32_t idx   = kk & 0xFFFFu;
            uint32_t sbits = maxbits - (kk >> 16);
            float score    = __uint_as_float(sbits);

            size_t base = (size_t)b * N + idx;
            const float4 a = *reinterpret_cast<const float4*>(anchors + base * 4);
            const float4 o = *reinterpret_cast<const float4*>(offsets + base * 4);

            float h  = a.z - a.x;
            float w  = a.w - a.y;
            float cy = a.x + 0.5f * h + o.x * h;
            float cx = a.y + 0.5f * w + o.y * w;
            float hh2 = h * expf(o.z);
            float ww  = w * expf(o.w);
            float y1 = fminf(fmaxf(cy - 0.5f * hh2, wy1), wy2);
            float x1 = fminf(fmaxf(cx - 0.5f * ww,  wx1), wx2);
            float y2 = fminf(fmaxf(cy + 0.5f * hh2, wy1), wy2);
            float x2 = fminf(fmaxf(cx + 0.5f * ww,  wx1), wx2);

            int ok = b * KSEL + (int)r;
            o_ai[ok*2 + 0] = (float)b;
            o_ai[ok*2 + 1] = (float)idx;
            o_bx[ok*4 + 0] = y1;
            o_bx[ok*4 + 1] = x1;
            o_bx[ok*4 + 2] = y2;
            o_bx[ok*4 + 3] = x2;
            o_cl[ok] = (float)cls_ws[base];
            o_sc[ok] = score;
            o_vd[ok] = (score > CONF_T) ? 1.0f : 0.0f;
        }
    } else {
        // ---- u64 LDS bitonic fallback (verified R21)
        for (unsigned k = 2; k <= CAND_CAP; k <<= 1) {
            for (unsigned j = k >> 1; j > 0; j >>= 1) {
                for (unsigned i = tid; i < CAND_CAP; i += 1024) {
                    unsigned ixj = i ^ j;
                    if (ixj > i) {
                        uint64_t a = cand[i], c2 = cand[ixj];
                        bool up = ((i & k) == 0);
                        if ((a > c2) == up) { cand[i] = c2; cand[ixj] = a; }
                    }
                }
                __syncthreads();
            }
        }
        for (uint32_t r = tid; r < W; r += 1024) {
            uint64_t kc = cand[r];
            if (kc == ~0ull) continue;
            uint32_t idx   = (uint32_t)kc;
            uint32_t sbits = ~(uint32_t)(kc >> 32);
            float score    = __uint_as_float(sbits);

            size_t base = (size_t)b * N + idx;
            const float4 a = *reinterpret_cast<const float4*>(anchors + base * 4);
            const float4 o = *reinterpret_cast<const float4*>(offsets + base * 4);

            float h  = a.z - a.x;
            float w  = a.w - a.y;
            float cy = a.x + 0.5f * h + o.x * h;
            float cx = a.y + 0.5f * w + o.y * w;
            float hh2 = h * expf(o.z);
            float ww  = w * expf(o.w);
            float y1 = fminf(fmaxf(cy - 0.5f * hh2, wy1), wy2);
            float x1 = fminf(fmaxf(cx - 0.5f * ww,  wx1), wx2);
            float y2 = fminf(fmaxf(cy + 0.5f * hh2, wy1), wy2);
            float x2 = fminf(fmaxf(cx + 0.5f * ww,  wx1), wx2);

            int ok = b * KSEL + (int)r;
            o_ai[ok*2 + 0] = (float)b;
            o_ai[ok*2 + 1] = (float)idx;
            o_bx[ok*4 + 0] = y1;
            o_bx[ok*4 + 1] = x1;
            o_bx[ok*4 + 2] = y2;
            o_bx[ok*4 + 3] = x2;
            o_cl[ok] = (float)cls_ws[base];
            o_sc[ok] = score;
            o_vd[ok] = (score > CONF_T) ? 1.0f : 0.0f;
        }
    }
}

extern "C" void kernel_launch(void* const* d_in, const int* in_sizes, int n_in,
                              void* d_out, int out_size, void* d_ws, size_t ws_size,
                              hipStream_t stream)
{
    const float* anchors = (const float*)d_in[0];
    const float* probs   = (const float*)d_in[1];
    const float* offsets = (const float*)d_in[2];
    const float* window  = (const float*)d_in[3];

    const int B = out_size / (9 * KSEL);
    const int N = in_sizes[0] / (B * 4);
    const int total = B * N;

    float* sc  = (float*)d_ws;
    int*   cls = (int*)((char*)d_ws + (size_t)total * 4);

    hipLaunchKernelGGL(score_argmax_kernel,
                       dim3((total + ROWS - 1) / ROWS), dim3(T1), 0, stream,
                       probs, sc, cls, total);

    hipLaunchKernelGGL(final_select_kernel, dim3(B), dim3(1024), 0, stream,
                       sc, cls, anchors, offsets, window,
                       (float*)d_out, N, B);
}